// Round 16
// baseline (475.083 us; speedup 1.0000x reference)
//
#include <hip/hip_runtime.h>
#include <stdint.h>

#define NN 100000
#define NE 1600000
#define NFLAT 12800000u  // NN*128
#define XRANGE 12500     // NN / 8 nodes per XCD range
#define XCHUNKS 782      // ceil(NE / 2048), 8 edges/thread
#define GBLK 782         // ceil(NN / 128) row-blocks for the layer kernels
#define MAXDEG 64        // Poisson(16): P(deg>64) ~ 1e-20
#define FILLB (8 * XCHUNKS)   // 6256 fill blocks (multiple of 8 -> XCD map ok)
#define CVTXB 12500           // cvt_x blocks
#define CVTWB 416             // cvt_w blocks
#define LDSW 136              // padded LDS row width (f16)
#define LDS_BYTES (128 * LDSW * 2 + 128 * 4 * 4)  // agg tile + mask words

typedef _Float16 f16;
typedef __attribute__((ext_vector_type(2))) _Float16 f16x2;
typedef __attribute__((ext_vector_type(4))) _Float16 f16x4;
typedef __attribute__((ext_vector_type(8))) _Float16 f16x8;
typedef __attribute__((ext_vector_type(4))) float f32x4;

// group-XOR swizzle (T2-style): 16B group g of row stored at g ^ (row&7)
#define SWZ(row, grp) ((((grp) ^ ((row) & 7)) << 3))

// ---------------- threefry2x32 (JAX-compatible) ----------------
__device__ __forceinline__ uint32_t rotl32(uint32_t x, int r) {
  return __builtin_amdgcn_alignbit(x, x, (32 - r) & 31);
}

__device__ __forceinline__ void tf2x32(uint32_t k0, uint32_t k1,
                                       uint32_t x0, uint32_t x1,
                                       uint32_t &o0, uint32_t &o1) {
  uint32_t ks2 = k0 ^ k1 ^ 0x1BD11BDAu;
#define TF_R(r) { x0 += x1; x1 = rotl32(x1, r); x1 ^= x0; }
  x0 += k0; x1 += k1;
  TF_R(13) TF_R(15) TF_R(26) TF_R(6)
  x0 += k1;  x1 += ks2 + 1u;
  TF_R(17) TF_R(29) TF_R(16) TF_R(24)
  x0 += ks2; x1 += k0 + 2u;
  TF_R(13) TF_R(15) TF_R(26) TF_R(6)
  x0 += k0;  x1 += k1 + 3u;
  TF_R(17) TF_R(29) TF_R(16) TF_R(24)
  x0 += k1;  x1 += ks2 + 4u;
  TF_R(13) TF_R(15) TF_R(26) TF_R(6)
  x0 += ks2; x1 += k0 + 5u;
#undef TF_R
  o0 = x0; o1 = x1;
}

static void tf2x32_host(uint32_t k0, uint32_t k1, uint32_t x0, uint32_t x1,
                        uint32_t *o0, uint32_t *o1) {
  uint32_t ks2 = k0 ^ k1 ^ 0x1BD11BDAu;
#define TF_R(r) { x0 += x1; x1 = (x1 << (r)) | (x1 >> (32 - (r))); x1 ^= x0; }
  x0 += k0; x1 += k1;
  TF_R(13) TF_R(15) TF_R(26) TF_R(6)
  x0 += k1;  x1 += ks2 + 1u;
  TF_R(17) TF_R(29) TF_R(16) TF_R(24)
  x0 += ks2; x1 += k0 + 2u;
  TF_R(13) TF_R(15) TF_R(26) TF_R(6)
  x0 += k0;  x1 += k1 + 3u;
  TF_R(17) TF_R(29) TF_R(16) TF_R(24)
  x0 += k1;  x1 += ks2 + 4u;
  TF_R(13) TF_R(15) TF_R(26) TF_R(6)
  x0 += ks2; x1 += k0 + 5u;
#undef TF_R
  *o0 = x0; *o1 = x1;
}

// ---------------- prep: fill + cvt_x + cvt_w in ONE kernel ----------------
__global__ __launch_bounds__(256) void prep_kernel(
    const int *__restrict__ src, const int *__restrict__ dst,
    int *__restrict__ cursor, int *__restrict__ col2,
    const float *__restrict__ x, f16 *__restrict__ xh,
    const float *__restrict__ w0, const float *__restrict__ w1,
    const float *__restrict__ w2, const float *__restrict__ lw,
    f16 *__restrict__ Wk0, f16 *__restrict__ Wk1, f16 *__restrict__ Wk2,
    f16 *__restrict__ WkL) {
  const int bid = blockIdx.x;
  const int tid = threadIdx.x;
  if (bid < FILLB) {
    int xr = bid & 7;
    int chunk = bid >> 3;
    int lo = xr * XRANGE, hi = lo + XRANGE;
    int base = chunk * 2048 + tid;
#pragma unroll
    for (int t = 0; t < 8; ++t) {
      int e = base + t * 256;
      if (e < NE) {
        int d = dst[e];
        if (d >= lo && d < hi) {
          int p = atomicAdd(&cursor[d], 1);
          if (p < MAXDEG) col2[d * MAXDEG + p] = src[e];
        }
      }
    }
  } else if (bid < FILLB + CVTXB) {
    uint32_t i = (uint32_t)(bid - FILLB) * 1024u + (uint32_t)tid * 4u;
    float4 v = *(const float4 *)(x + i);
    f16x4 o;
    o[0] = (f16)v.x; o[1] = (f16)v.y; o[2] = (f16)v.z; o[3] = (f16)v.w;
    *(f16x4 *)(xh + i) = o;
  } else {
    int t = (bid - FILLB - CVTXB) * 256 + tid;
    if (t < 3 * 32768) {
      int wi = t >> 15, r = t & 32767;  // r = k*128 + c
      int k = r >> 7, c = r & 127;
      const float *w = (wi == 0) ? w0 : ((wi == 1) ? w1 : w2);
      f16 *o = (wi == 0) ? Wk0 : ((wi == 1) ? Wk1 : Wk2);
      o[c * 256 + k] = (f16)w[r];
    } else {
      int r = t - 3 * 32768;  // r = k*64 + c, r < 8192
      int k = r >> 6, c = r & 63;
      WkL[c * 128 + k] = (f16)lw[r];
    }
  }
}

// ---------------- fused layer: agg + mask + [agg,h]@W + relu + dropout -----
// Block = 128 rows, 8 waves. Phase 1: wave wv aggregates rows [wv*16,+16)
// (one-wave-per-node gather, 4-edge x 16B lanes, 16-edge unroll -> bit-
// identical to the standalone agg) into a swizzled LDS tile; lane 0 stores
// the node's 4 packed dropout-mask words to LDS. Phase 2: B-stationary GEMM,
// wave owns 16 output cols; A agg-half from LDS, hin-half coalesced global.
// FINAL: strip accumulators held in VGPRs; after a sync the agg tile is
// overwritten with h3 and the 128->64 final GEMM runs from LDS (h3 never
// touches global). Eliminates the global agg/mask buffers (51+ MB/layer).
template <int FINAL>
__global__ __launch_bounds__(512, 6) void sage_layer(
    const f16 *__restrict__ hin, const int *__restrict__ deg,
    const int *__restrict__ col2, const f16 *__restrict__ Wk,
    const float *__restrict__ bias, f16 *__restrict__ hout,
    const f16 *__restrict__ WkL, const float *__restrict__ lbias,
    float *__restrict__ outp, uint32_t mk0, uint32_t mk1) {
  extern __shared__ char smem[];
  f16 (*agl)[LDSW] = (f16(*)[LDSW])smem;
  uint32_t *mws = (uint32_t *)(smem + 128 * LDSW * 2);
  const int tid = threadIdx.x;
  const int lane = tid & 63;
  const int wv = tid >> 6;  // 0..7
  const int blk_row0 = blockIdx.x * 128;

  // ---------- phase 1: aggregate 16 nodes per wave + mask ----------
  {
    const int q4 = lane >> 4;
    const int r = lane & 15;
    for (int ii = 0; ii < 16; ++ii) {
      const int ln = wv * 16 + ii;
      const int n = blk_row0 + ln;
      uint32_t j0 = (uint32_t)n * 128u + (uint32_t)lane;
      uint32_t o0, o1, p0, p1;
      tf2x32(mk0, mk1, 0u, j0, o0, o1);
      tf2x32(mk0, mk1, 0u, j0 + 64u, p0, p1);
      unsigned long long blo = __ballot((int)(o0 ^ o1) >= 0);
      unsigned long long bhi = __ballot((int)(p0 ^ p1) >= 0);
      if (lane == 0) {
        uint4 mv;
        mv.x = (uint32_t)blo; mv.y = (uint32_t)(blo >> 32);
        mv.z = (uint32_t)bhi; mv.w = (uint32_t)(bhi >> 32);
        *(uint4 *)&mws[ln * 4] = mv;
      }
      const int beg = n * MAXDEG;
      int d = (n < NN) ? min(deg[n], MAXDEG) : 0;
      float s0 = 0.f, s1 = 0.f, s2 = 0.f, s3 = 0.f;
      float s4 = 0.f, s5 = 0.f, s6 = 0.f, s7 = 0.f;
      int i = 0;
      for (; i + 16 <= d; i += 16) {
        int c0 = col2[beg + i + q4];
        int c1 = col2[beg + i + 4 + q4];
        int c2 = col2[beg + i + 8 + q4];
        int c3 = col2[beg + i + 12 + q4];
        f16x8 v0 = ((const f16x8 *)(hin + (size_t)c0 * 128))[r];
        f16x8 v1 = ((const f16x8 *)(hin + (size_t)c1 * 128))[r];
        f16x8 v2 = ((const f16x8 *)(hin + (size_t)c2 * 128))[r];
        f16x8 v3 = ((const f16x8 *)(hin + (size_t)c3 * 128))[r];
        s0 += (float)v0[0] + (float)v1[0] + (float)v2[0] + (float)v3[0];
        s1 += (float)v0[1] + (float)v1[1] + (float)v2[1] + (float)v3[1];
        s2 += (float)v0[2] + (float)v1[2] + (float)v2[2] + (float)v3[2];
        s3 += (float)v0[3] + (float)v1[3] + (float)v2[3] + (float)v3[3];
        s4 += (float)v0[4] + (float)v1[4] + (float)v2[4] + (float)v3[4];
        s5 += (float)v0[5] + (float)v1[5] + (float)v2[5] + (float)v3[5];
        s6 += (float)v0[6] + (float)v1[6] + (float)v2[6] + (float)v3[6];
        s7 += (float)v0[7] + (float)v1[7] + (float)v2[7] + (float)v3[7];
      }
      for (; i + 8 <= d; i += 8) {
        int c0 = col2[beg + i + q4];
        int c1 = col2[beg + i + 4 + q4];
        f16x8 v0 = ((const f16x8 *)(hin + (size_t)c0 * 128))[r];
        f16x8 v1 = ((const f16x8 *)(hin + (size_t)c1 * 128))[r];
        s0 += (float)v0[0] + (float)v1[0];
        s1 += (float)v0[1] + (float)v1[1];
        s2 += (float)v0[2] + (float)v1[2];
        s3 += (float)v0[3] + (float)v1[3];
        s4 += (float)v0[4] + (float)v1[4];
        s5 += (float)v0[5] + (float)v1[5];
        s6 += (float)v0[6] + (float)v1[6];
        s7 += (float)v0[7] + (float)v1[7];
      }
      for (; i + 4 <= d; i += 4) {
        int c = col2[beg + i + q4];
        f16x8 v = ((const f16x8 *)(hin + (size_t)c * 128))[r];
        s0 += (float)v[0]; s1 += (float)v[1];
        s2 += (float)v[2]; s3 += (float)v[3];
        s4 += (float)v[4]; s5 += (float)v[5];
        s6 += (float)v[6]; s7 += (float)v[7];
      }
      if (i < d && q4 < d - i) {
        int c = col2[beg + i + q4];
        f16x8 v = ((const f16x8 *)(hin + (size_t)c * 128))[r];
        s0 += (float)v[0]; s1 += (float)v[1];
        s2 += (float)v[2]; s3 += (float)v[3];
        s4 += (float)v[4]; s5 += (float)v[5];
        s6 += (float)v[6]; s7 += (float)v[7];
      }
      s0 += __shfl_xor(s0, 16); s0 += __shfl_xor(s0, 32);
      s1 += __shfl_xor(s1, 16); s1 += __shfl_xor(s1, 32);
      s2 += __shfl_xor(s2, 16); s2 += __shfl_xor(s2, 32);
      s3 += __shfl_xor(s3, 16); s3 += __shfl_xor(s3, 32);
      s4 += __shfl_xor(s4, 16); s4 += __shfl_xor(s4, 32);
      s5 += __shfl_xor(s5, 16); s5 += __shfl_xor(s5, 32);
      s6 += __shfl_xor(s6, 16); s6 += __shfl_xor(s6, 32);
      s7 += __shfl_xor(s7, 16); s7 += __shfl_xor(s7, 32);
      if (q4 == 0) {
        float inv = 1.0f / (float)max(d, 1);
        f16x8 o;
        o[0] = (f16)(s0 * inv); o[1] = (f16)(s1 * inv);
        o[2] = (f16)(s2 * inv); o[3] = (f16)(s3 * inv);
        o[4] = (f16)(s4 * inv); o[5] = (f16)(s5 * inv);
        o[6] = (f16)(s6 * inv); o[7] = (f16)(s7 * inv);
        *(f16x8 *)&agl[ln][SWZ(ln, r)] = o;
      }
    }
  }
  __syncthreads();

  // ---------- phase 2: GEMM, wave owns 16 output cols ----------
  const int hi = lane >> 4;
  const int kg = hi * 8;
  const int col_lo = lane & 15;
  const int c = wv * 16 + col_lo;
  f16x8 Bf[8];
#pragma unroll
  for (int ks = 0; ks < 8; ++ks)
    Bf[ks] = *(const f16x8 *)(Wk + (size_t)c * 256 + ks * 32 + kg);
  const float bv = bias[c];
  const int mwsel = wv >> 1;
  const int sh = ((wv & 1) << 4) | col_lo;

  f32x4 accAll[FINAL ? 8 : 1];
#pragma unroll
  for (int s = 0; s < 8; ++s) {
    const int ar = blk_row0 + s * 16 + col_lo;
    const int lr = s * 16 + col_lo;
    const bool rowok = ar < NN;
    f16x8 Af[8];
#pragma unroll
    for (int ks = 0; ks < 4; ++ks)
      Af[ks] = *(const f16x8 *)&agl[lr][SWZ(lr, 4 * ks + hi)];
#pragma unroll
    for (int ks = 4; ks < 8; ++ks)
      Af[ks] = rowok
                   ? *(const f16x8 *)(hin + (size_t)ar * 128 + (ks - 4) * 32 + kg)
                   : (f16x8){};
    f32x4 acc = {0.f, 0.f, 0.f, 0.f};
#pragma unroll
    for (int ks = 0; ks < 8; ++ks)
      acc = __builtin_amdgcn_mfma_f32_16x16x32_f16(Af[ks], Bf[ks], acc, 0, 0, 0);
    if constexpr (!FINAL) {
      const int rbase = blk_row0 + s * 16 + hi * 4;
#pragma unroll
      for (int r = 0; r < 4; ++r) {
        const int row = rbase + r;
        if (row < NN) {
          uint32_t mw = mws[(row - blk_row0) * 4 + mwsel];
          float z = acc[r] + bv;
          z = (z > 0.f && ((mw >> sh) & 1u)) ? z * 2.f : 0.f;
          hout[(size_t)row * 128 + c] = (f16)z;
        }
      }
    } else {
      accAll[s] = acc;
    }
  }

  if constexpr (FINAL) {
    __syncthreads();  // all waves done reading the agg tile
#pragma unroll
    for (int s = 0; s < 8; ++s) {
      const int rb = s * 16 + hi * 4;
#pragma unroll
      for (int r = 0; r < 4; ++r) {
        const int lr = rb + r;
        uint32_t mw = mws[lr * 4 + mwsel];
        float z = accAll[s][r] + bv;
        z = (z > 0.f && ((mw >> sh) & 1u)) ? z * 2.f : 0.f;
        agl[lr][SWZ(lr, c >> 3) | (c & 7)] = (f16)z;  // overwrite tile w/ h3
      }
    }
    __syncthreads();
    // final: out = h3 @ WkL + lb; wave (cg,rh) does cols cg*16+.., strips rh*4..
    const int cg = wv & 3;
    const int rh = wv >> 2;
    const int fc = cg * 16 + col_lo;
    f16x8 Bf2[4];
#pragma unroll
    for (int ks = 0; ks < 4; ++ks)
      Bf2[ks] = *(const f16x8 *)(WkL + (size_t)fc * 128 + ks * 32 + kg);
    const float fbv = lbias[fc];
#pragma unroll
    for (int s2 = 0; s2 < 4; ++s2) {
      const int s = rh * 4 + s2;
      const int lr = s * 16 + col_lo;
      f32x4 acc = {0.f, 0.f, 0.f, 0.f};
#pragma unroll
      for (int ks = 0; ks < 4; ++ks) {
        f16x8 a = *(const f16x8 *)&agl[lr][SWZ(lr, 4 * ks + hi)];
        acc = __builtin_amdgcn_mfma_f32_16x16x32_f16(a, Bf2[ks], acc, 0, 0, 0);
      }
      const int rbase = blk_row0 + s * 16 + hi * 4;
#pragma unroll
      for (int r = 0; r < 4; ++r) {
        const int row = rbase + r;
        if (row < NN) outp[(size_t)row * 64 + fc] = acc[r] + fbv;
      }
    }
  }
}

extern "C" void kernel_launch(void *const *d_in, const int *in_sizes, int n_in,
                              void *d_out, int out_size, void *d_ws,
                              size_t ws_size, hipStream_t stream) {
  (void)in_sizes; (void)n_in; (void)out_size; (void)ws_size;
  const float *x = (const float *)d_in[0];
  const int *edge = (const int *)d_in[1];
  const int *src = edge;
  const int *dst = edge + NE;
  const float *w0 = (const float *)d_in[2];
  const float *b0 = (const float *)d_in[3];
  const float *w1 = (const float *)d_in[4];
  const float *b1 = (const float *)d_in[5];
  const float *w2 = (const float *)d_in[6];
  const float *b2 = (const float *)d_in[7];
  const float *lw = (const float *)d_in[8];
  const float *lb = (const float *)d_in[9];
  float *out = (float *)d_out;

  char *ws = (char *)d_ws;
  f16 *xh  = (f16 *)ws; ws += (size_t)NN * 128 * 2;
  f16 *h1  = (f16 *)ws; ws += (size_t)NN * 128 * 2;
  f16 *h2  = (f16 *)ws; ws += (size_t)NN * 128 * 2;
  f16 *Wk0 = (f16 *)ws; ws += 256 * 128 * 2;
  f16 *Wk1 = (f16 *)ws; ws += 256 * 128 * 2;
  f16 *Wk2 = (f16 *)ws; ws += 256 * 128 * 2;
  f16 *WkL = (f16 *)ws; ws += 128 * 64 * 2;
  int *cursor = (int *)ws; ws += (size_t)NN * 4;
  int *col2 = (int *)ws;   ws += (size_t)NN * MAXDEG * 4;

  uint32_t fk[3][2];
  for (int i = 0; i < 3; ++i)
    tf2x32_host(0u, 42u, 0u, (uint32_t)i, &fk[i][0], &fk[i][1]);

  hipMemsetAsync(cursor, 0, (size_t)NN * 4, stream);
  prep_kernel<<<FILLB + CVTXB + CVTWB, 256, 0, stream>>>(
      src, dst, cursor, col2, x, xh, w0, w1, w2, lw, Wk0, Wk1, Wk2, WkL);

  sage_layer<0><<<GBLK, 512, LDS_BYTES, stream>>>(
      xh, cursor, col2, Wk0, b0, h1, nullptr, nullptr, nullptr,
      fk[0][0], fk[0][1]);
  sage_layer<0><<<GBLK, 512, LDS_BYTES, stream>>>(
      h1, cursor, col2, Wk1, b1, h2, nullptr, nullptr, nullptr,
      fk[1][0], fk[1][1]);
  sage_layer<1><<<GBLK, 512, LDS_BYTES, stream>>>(
      h2, cursor, col2, Wk2, b2, nullptr, WkL, lb, out,
      fk[2][0], fk[2][1]);
}

// Round 17
// 410.154 us; speedup vs baseline: 1.1583x; 1.1583x over previous
//
#include <hip/hip_runtime.h>
#include <stdint.h>

#define NN 100000
#define NE 1600000
#define NFLAT 12800000u  // NN*128
#define XRANGE 12500     // NN / 8 nodes per XCD range
#define XCHUNKS 782      // ceil(NE / 2048), 8 edges/thread
#define GBLK 1563        // ceil(NN / 64) row-blocks for the GEMMs
#define MAXDEG 64        // Poisson(16): P(deg>64) ~ 1e-20
#define FILLB (8 * XCHUNKS)   // 6256 fill blocks (multiple of 8 -> XCD map ok)
#define CVTXB 12500           // cvt_x blocks
#define CVTWB 416             // cvt_w blocks
#define LDSW 136              // padded LDS row width (f16) for FINAL tile

typedef _Float16 f16;
typedef __attribute__((ext_vector_type(2))) _Float16 f16x2;
typedef __attribute__((ext_vector_type(4))) _Float16 f16x4;
typedef __attribute__((ext_vector_type(8))) _Float16 f16x8;
typedef __attribute__((ext_vector_type(4))) float f32x4;

// ---------------- threefry2x32 (JAX-compatible) ----------------
__device__ __forceinline__ uint32_t rotl32(uint32_t x, int r) {
  return __builtin_amdgcn_alignbit(x, x, (32 - r) & 31);
}

__device__ __forceinline__ void tf2x32(uint32_t k0, uint32_t k1,
                                       uint32_t x0, uint32_t x1,
                                       uint32_t &o0, uint32_t &o1) {
  uint32_t ks2 = k0 ^ k1 ^ 0x1BD11BDAu;
#define TF_R(r) { x0 += x1; x1 = rotl32(x1, r); x1 ^= x0; }
  x0 += k0; x1 += k1;
  TF_R(13) TF_R(15) TF_R(26) TF_R(6)
  x0 += k1;  x1 += ks2 + 1u;
  TF_R(17) TF_R(29) TF_R(16) TF_R(24)
  x0 += ks2; x1 += k0 + 2u;
  TF_R(13) TF_R(15) TF_R(26) TF_R(6)
  x0 += k0;  x1 += k1 + 3u;
  TF_R(17) TF_R(29) TF_R(16) TF_R(24)
  x0 += k1;  x1 += ks2 + 4u;
  TF_R(13) TF_R(15) TF_R(26) TF_R(6)
  x0 += ks2; x1 += k0 + 5u;
#undef TF_R
  o0 = x0; o1 = x1;
}

static void tf2x32_host(uint32_t k0, uint32_t k1, uint32_t x0, uint32_t x1,
                        uint32_t *o0, uint32_t *o1) {
  uint32_t ks2 = k0 ^ k1 ^ 0x1BD11BDAu;
#define TF_R(r) { x0 += x1; x1 = (x1 << (r)) | (x1 >> (32 - (r))); x1 ^= x0; }
  x0 += k0; x1 += k1;
  TF_R(13) TF_R(15) TF_R(26) TF_R(6)
  x0 += k1;  x1 += ks2 + 1u;
  TF_R(17) TF_R(29) TF_R(16) TF_R(24)
  x0 += ks2; x1 += k0 + 2u;
  TF_R(13) TF_R(15) TF_R(26) TF_R(6)
  x0 += k0;  x1 += k1 + 3u;
  TF_R(17) TF_R(29) TF_R(16) TF_R(24)
  x0 += k1;  x1 += ks2 + 4u;
  TF_R(13) TF_R(15) TF_R(26) TF_R(6)
  x0 += ks2; x1 += k0 + 5u;
#undef TF_R
  *o0 = x0; *o1 = x1;
}

// ---------------- prep: fill + cvt_x + cvt_w in ONE kernel ----------------
__global__ __launch_bounds__(256) void prep_kernel(
    const int *__restrict__ src, const int *__restrict__ dst,
    int *__restrict__ cursor, int *__restrict__ col2,
    const float *__restrict__ x, f16 *__restrict__ xh,
    const float *__restrict__ w0, const float *__restrict__ w1,
    const float *__restrict__ w2, const float *__restrict__ lw,
    f16 *__restrict__ Wk0, f16 *__restrict__ Wk1, f16 *__restrict__ Wk2,
    f16 *__restrict__ WkL) {
  const int bid = blockIdx.x;
  const int tid = threadIdx.x;
  if (bid < FILLB) {
    int xr = bid & 7;
    int chunk = bid >> 3;
    int lo = xr * XRANGE, hi = lo + XRANGE;
    int base = chunk * 2048 + tid;
#pragma unroll
    for (int t = 0; t < 8; ++t) {
      int e = base + t * 256;
      if (e < NE) {
        int d = dst[e];
        if (d >= lo && d < hi) {
          int p = atomicAdd(&cursor[d], 1);
          if (p < MAXDEG) col2[d * MAXDEG + p] = src[e];
        }
      }
    }
  } else if (bid < FILLB + CVTXB) {
    uint32_t i = (uint32_t)(bid - FILLB) * 1024u + (uint32_t)tid * 4u;
    float4 v = *(const float4 *)(x + i);
    f16x4 o;
    o[0] = (f16)v.x; o[1] = (f16)v.y; o[2] = (f16)v.z; o[3] = (f16)v.w;
    *(f16x4 *)(xh + i) = o;
  } else {
    int t = (bid - FILLB - CVTXB) * 256 + tid;
    if (t < 3 * 32768) {
      int wi = t >> 15, r = t & 32767;  // r = k*128 + c
      int k = r >> 7, c = r & 127;
      const float *w = (wi == 0) ? w0 : ((wi == 1) ? w1 : w2);
      f16 *o = (wi == 0) ? Wk0 : ((wi == 1) ? Wk1 : Wk2);
      o[c * 256 + k] = (f16)w[r];
    } else {
      int r = t - 3 * 32768;  // r = k*64 + c, r < 8192
      int k = r >> 6, c = r & 63;
      WkL[c * 128 + k] = (f16)lw[r];
    }
  }
}

// ---------------- mean aggregation + fused dropout-mask gen ----------------
// One wave per node, 4-edge x 16B-lane gather (lane = q4*16 + r), 16-edge
// unroll (4 independent f16x8 gathers in flight). 25000 blocks -> gather
// runs at full TLP (R16 lesson: coupling this to the GEMM grid starves it).
__global__ __launch_bounds__(256) void agg_kernel(const f16 *__restrict__ h,
                                                  const int *__restrict__ deg,
                                                  const int *__restrict__ col2,
                                                  f16 *__restrict__ agg,
                                                  uint32_t *__restrict__ mrow,
                                                  uint32_t mk0, uint32_t mk1) {
  int wid = threadIdx.x >> 6;
  int lane = threadIdx.x & 63;
  int n = (blockIdx.x & 7) * XRANGE + (blockIdx.x >> 3) * 4 + wid;

  // ---- fused mask (independent VALU work; hides under gather latency)
  {
    uint32_t j0 = (uint32_t)n * 128u + (uint32_t)lane;
    uint32_t o0, o1, p0, p1;
    tf2x32(mk0, mk1, 0u, j0, o0, o1);
    tf2x32(mk0, mk1, 0u, j0 + 64u, p0, p1);
    unsigned long long blo = __ballot((int)(o0 ^ o1) >= 0);
    unsigned long long bhi = __ballot((int)(p0 ^ p1) >= 0);
    if (lane == 0) {
      uint4 mv;
      mv.x = (uint32_t)blo; mv.y = (uint32_t)(blo >> 32);
      mv.z = (uint32_t)bhi; mv.w = (uint32_t)(bhi >> 32);
      *(uint4 *)(mrow + (size_t)n * 4) = mv;
    }
  }

  const int beg = n * MAXDEG;
  int d = min(deg[n], MAXDEG);
  const int q4 = lane >> 4;
  const int r = lane & 15;
  float s0 = 0.f, s1 = 0.f, s2 = 0.f, s3 = 0.f;
  float s4 = 0.f, s5 = 0.f, s6 = 0.f, s7 = 0.f;
  int i = 0;
  for (; i + 16 <= d; i += 16) {
    int c0 = col2[beg + i + q4];
    int c1 = col2[beg + i + 4 + q4];
    int c2 = col2[beg + i + 8 + q4];
    int c3 = col2[beg + i + 12 + q4];
    f16x8 v0 = ((const f16x8 *)(h + (size_t)c0 * 128))[r];
    f16x8 v1 = ((const f16x8 *)(h + (size_t)c1 * 128))[r];
    f16x8 v2 = ((const f16x8 *)(h + (size_t)c2 * 128))[r];
    f16x8 v3 = ((const f16x8 *)(h + (size_t)c3 * 128))[r];
    s0 += (float)v0[0] + (float)v1[0] + (float)v2[0] + (float)v3[0];
    s1 += (float)v0[1] + (float)v1[1] + (float)v2[1] + (float)v3[1];
    s2 += (float)v0[2] + (float)v1[2] + (float)v2[2] + (float)v3[2];
    s3 += (float)v0[3] + (float)v1[3] + (float)v2[3] + (float)v3[3];
    s4 += (float)v0[4] + (float)v1[4] + (float)v2[4] + (float)v3[4];
    s5 += (float)v0[5] + (float)v1[5] + (float)v2[5] + (float)v3[5];
    s6 += (float)v0[6] + (float)v1[6] + (float)v2[6] + (float)v3[6];
    s7 += (float)v0[7] + (float)v1[7] + (float)v2[7] + (float)v3[7];
  }
  for (; i + 8 <= d; i += 8) {
    int c0 = col2[beg + i + q4];
    int c1 = col2[beg + i + 4 + q4];
    f16x8 v0 = ((const f16x8 *)(h + (size_t)c0 * 128))[r];
    f16x8 v1 = ((const f16x8 *)(h + (size_t)c1 * 128))[r];
    s0 += (float)v0[0] + (float)v1[0];
    s1 += (float)v0[1] + (float)v1[1];
    s2 += (float)v0[2] + (float)v1[2];
    s3 += (float)v0[3] + (float)v1[3];
    s4 += (float)v0[4] + (float)v1[4];
    s5 += (float)v0[5] + (float)v1[5];
    s6 += (float)v0[6] + (float)v1[6];
    s7 += (float)v0[7] + (float)v1[7];
  }
  for (; i + 4 <= d; i += 4) {
    int c = col2[beg + i + q4];
    f16x8 v = ((const f16x8 *)(h + (size_t)c * 128))[r];
    s0 += (float)v[0]; s1 += (float)v[1];
    s2 += (float)v[2]; s3 += (float)v[3];
    s4 += (float)v[4]; s5 += (float)v[5];
    s6 += (float)v[6]; s7 += (float)v[7];
  }
  if (i < d && q4 < d - i) {
    int c = col2[beg + i + q4];
    f16x8 v = ((const f16x8 *)(h + (size_t)c * 128))[r];
    s0 += (float)v[0]; s1 += (float)v[1];
    s2 += (float)v[2]; s3 += (float)v[3];
    s4 += (float)v[4]; s5 += (float)v[5];
    s6 += (float)v[6]; s7 += (float)v[7];
  }
  s0 += __shfl_xor(s0, 16); s0 += __shfl_xor(s0, 32);
  s1 += __shfl_xor(s1, 16); s1 += __shfl_xor(s1, 32);
  s2 += __shfl_xor(s2, 16); s2 += __shfl_xor(s2, 32);
  s3 += __shfl_xor(s3, 16); s3 += __shfl_xor(s3, 32);
  s4 += __shfl_xor(s4, 16); s4 += __shfl_xor(s4, 32);
  s5 += __shfl_xor(s5, 16); s5 += __shfl_xor(s5, 32);
  s6 += __shfl_xor(s6, 16); s6 += __shfl_xor(s6, 32);
  s7 += __shfl_xor(s7, 16); s7 += __shfl_xor(s7, 32);
  if (q4 == 0) {
    float inv = 1.0f / (float)max(d, 1);
    f16x8 o;
    o[0] = (f16)(s0 * inv); o[1] = (f16)(s1 * inv);
    o[2] = (f16)(s2 * inv); o[3] = (f16)(s3 * inv);
    o[4] = (f16)(s4 * inv); o[5] = (f16)(s5 * inv);
    o[6] = (f16)(s6 * inv); o[7] = (f16)(s7 * inv);
    ((f16x8 *)(agg + (size_t)n * 128))[r] = o;
  }
}

// ---------------- fused [agg,h]@W + b -> relu -> dropout (MFMA f16) --------
// B-stationary, 64-row blocks (grid 1563): same work as the 128-row version
// but 2x resident waves/SIMD — the R4/R14 counters showed occupancy was
// grid-limited (~3 waves/SIMD), and the kernel is latency-bound. FINAL:
// epilogue keeps h3 in a padded LDS tile and runs the 128->64 GEMM from
// LDS (h3 never touches global).
template <int FINAL>
__global__ __launch_bounds__(256) void sage_gemm_f16(
    const f16 *__restrict__ agg, const f16 *__restrict__ hin,
    const f16 *__restrict__ Wk, const float *__restrict__ bias,
    const uint32_t *__restrict__ mask, f16 *__restrict__ hout,
    const f16 *__restrict__ WkL, const float *__restrict__ lb,
    float *__restrict__ outp) {
  extern __shared__ char smem[];
  f16 (*hl)[LDSW] = (f16(*)[LDSW])smem;
  const int tid = threadIdx.x;
  const int lane = tid & 63;
  const int wv = tid >> 6;
  const int blk_row0 = blockIdx.x * 64;
  const int kg = (lane >> 4) * 8;
  const int col_lo = lane & 15;

  f16x8 Bf[2][8];
#pragma unroll
  for (int t = 0; t < 2; ++t) {
    const int colb = wv * 32 + t * 16 + col_lo;
#pragma unroll
    for (int ks = 0; ks < 8; ++ks)
      Bf[t][ks] = *(const f16x8 *)(Wk + (size_t)colb * 256 + ks * 32 + kg);
  }
  const float bv0 = bias[wv * 32 + col_lo];
  const float bv1 = bias[wv * 32 + 16 + col_lo];

#pragma unroll 2
  for (int s = 0; s < 4; ++s) {
    const int row0 = blk_row0 + s * 16;
    const int ar = row0 + col_lo;
    const bool rowok = ar < NN;
    f16x8 Af[8];
#pragma unroll
    for (int ks = 0; ks < 8; ++ks) {
      const f16 *asrc = (ks < 4)
                            ? (agg + (size_t)ar * 128 + ks * 32 + kg)
                            : (hin + (size_t)ar * 128 + (ks - 4) * 32 + kg);
      Af[ks] = rowok ? *(const f16x8 *)asrc : (f16x8){};
    }
    f32x4 acc0 = {0.f, 0.f, 0.f, 0.f}, acc1 = {0.f, 0.f, 0.f, 0.f};
#pragma unroll
    for (int ks = 0; ks < 8; ++ks) {
      acc0 = __builtin_amdgcn_mfma_f32_16x16x32_f16(Af[ks], Bf[0][ks], acc0, 0, 0, 0);
      acc1 = __builtin_amdgcn_mfma_f32_16x16x32_f16(Af[ks], Bf[1][ks], acc1, 0, 0, 0);
    }
    const int rbase = row0 + (lane >> 4) * 4;
    const int c0 = wv * 32 + col_lo;
#pragma unroll
    for (int r = 0; r < 4; ++r) {
      const int row = rbase + r;
      if (row < NN) {
        uint32_t mw = mask[(size_t)row * 4 + wv];  // both tiles share word wv
        float z0 = acc0[r] + bv0;
        float z1 = acc1[r] + bv1;
        z0 = (z0 > 0.f && ((mw >> col_lo) & 1u)) ? z0 * 2.f : 0.f;
        z1 = (z1 > 0.f && ((mw >> (16 + col_lo)) & 1u)) ? z1 * 2.f : 0.f;
        if constexpr (FINAL) {
          const int lr = row - blk_row0;
          hl[lr][c0] = (f16)z0;
          hl[lr][c0 + 16] = (f16)z1;
        } else {
          hout[(size_t)row * 128 + c0] = (f16)z0;
          hout[(size_t)row * 128 + c0 + 16] = (f16)z1;
        }
      }
    }
  }

  if constexpr (FINAL) {
    __syncthreads();
    // wave wv owns out cols [wv*16, +16); A from LDS (pad -> benign banks)
    const int c = wv * 16 + col_lo;
    f16x8 Bf2[4];
#pragma unroll
    for (int ks = 0; ks < 4; ++ks)
      Bf2[ks] = *(const f16x8 *)(WkL + (size_t)c * 128 + ks * 32 + kg);
    const float bv = lb[c];
#pragma unroll 2
    for (int s = 0; s < 4; ++s) {
      const int lr = s * 16 + col_lo;
      f32x4 acc = {0.f, 0.f, 0.f, 0.f};
#pragma unroll
      for (int ks = 0; ks < 4; ++ks) {
        f16x8 a = *(const f16x8 *)&hl[lr][ks * 32 + kg];
        acc = __builtin_amdgcn_mfma_f32_16x16x32_f16(a, Bf2[ks], acc, 0, 0, 0);
      }
      const int rbase = blk_row0 + s * 16 + (lane >> 4) * 4;
#pragma unroll
      for (int r = 0; r < 4; ++r) {
        const int row = rbase + r;
        if (row < NN) outp[(size_t)row * 64 + c] = acc[r] + bv;
      }
    }
  }
}

extern "C" void kernel_launch(void *const *d_in, const int *in_sizes, int n_in,
                              void *d_out, int out_size, void *d_ws,
                              size_t ws_size, hipStream_t stream) {
  (void)in_sizes; (void)n_in; (void)out_size; (void)ws_size;
  const float *x = (const float *)d_in[0];
  const int *edge = (const int *)d_in[1];
  const int *src = edge;
  const int *dst = edge + NE;
  const float *w0 = (const float *)d_in[2];
  const float *b0 = (const float *)d_in[3];
  const float *w1 = (const float *)d_in[4];
  const float *b1 = (const float *)d_in[5];
  const float *w2 = (const float *)d_in[6];
  const float *b2 = (const float *)d_in[7];
  const float *lw = (const float *)d_in[8];
  const float *lb = (const float *)d_in[9];
  float *out = (float *)d_out;

  char *ws = (char *)d_ws;
  f16 *xh  = (f16 *)ws; ws += (size_t)NN * 128 * 2;
  f16 *h1  = (f16 *)ws; ws += (size_t)NN * 128 * 2;
  f16 *h2  = (f16 *)ws; ws += (size_t)NN * 128 * 2;
  f16 *agg = (f16 *)ws; ws += (size_t)NN * 128 * 2;
  f16 *Wk0 = (f16 *)ws; ws += 256 * 128 * 2;
  f16 *Wk1 = (f16 *)ws; ws += 256 * 128 * 2;
  f16 *Wk2 = (f16 *)ws; ws += 256 * 128 * 2;
  f16 *WkL = (f16 *)ws; ws += 128 * 64 * 2;
  int *cursor = (int *)ws; ws += (size_t)NN * 4;
  int *col2 = (int *)ws;   ws += (size_t)NN * MAXDEG * 4;
  uint32_t *m0 = (uint32_t *)ws; ws += (size_t)(NFLAT / 32) * 4;
  uint32_t *m1 = (uint32_t *)ws; ws += (size_t)(NFLAT / 32) * 4;
  uint32_t *m2 = (uint32_t *)ws; ws += (size_t)(NFLAT / 32) * 4;

  uint32_t fk[3][2];
  for (int i = 0; i < 3; ++i)
    tf2x32_host(0u, 42u, 0u, (uint32_t)i, &fk[i][0], &fk[i][1]);

  hipMemsetAsync(cursor, 0, (size_t)NN * 4, stream);
  prep_kernel<<<FILLB + CVTXB + CVTWB, 256, 0, stream>>>(
      src, dst, cursor, col2, x, xh, w0, w1, w2, lw, Wk0, Wk1, Wk2, WkL);

  // layer 0 (agg also generates m0)
  agg_kernel<<<NN / 4, 256, 0, stream>>>(xh, cursor, col2, agg, m0,
                                         fk[0][0], fk[0][1]);
  sage_gemm_f16<0><<<GBLK, 256, 0, stream>>>(agg, xh, Wk0, b0, m0, h1,
                                             nullptr, nullptr, nullptr);
  // layer 1 (agg also generates m1)
  agg_kernel<<<NN / 4, 256, 0, stream>>>(h1, cursor, col2, agg, m1,
                                         fk[1][0], fk[1][1]);
  sage_gemm_f16<0><<<GBLK, 256, 0, stream>>>(agg, h1, Wk1, b1, m1, h2,
                                             nullptr, nullptr, nullptr);
  // layer 2 fused with final linear: h3 lives only in LDS
  agg_kernel<<<NN / 4, 256, 0, stream>>>(h2, cursor, col2, agg, m2,
                                         fk[2][0], fk[2][1]);
  sage_gemm_f16<1><<<GBLK, 256, 64 * LDSW * 2, stream>>>(
      agg, h2, Wk2, b2, m2, nullptr, WkL, lb, out);
}